// Round 1
// baseline (241.518 us; speedup 1.0000x reference)
//
#include <hip/hip_runtime.h>

typedef __attribute__((ext_vector_type(8))) _Float16 f16x8;   // 8 fp16 = 4 VGPRs
typedef __attribute__((ext_vector_type(4))) float f32x4;

constexpr int kC  = 128;
constexpr int kCH = 64;
constexpr int kN  = 4096;
constexpr float kLog2e = 1.4426950408889634f;

__device__ __forceinline__ unsigned pkrtz(float a, float b) {
    union { __fp16 __attribute__((ext_vector_type(2))) v; unsigned u; } cv;
    cv.v = __builtin_amdgcn_cvt_pkrtz(a, b);
    return cv.u;
}

// direct global->LDS DMA, 16B per lane, dest = wave-uniform base + lane*16
__device__ __forceinline__ void g2l16(const unsigned short* g, unsigned short* l) {
    __builtin_amdgcn_global_load_lds(
        (const __attribute__((address_space(1))) unsigned int*)(g),
        (__attribute__((address_space(3))) unsigned int*)(l),
        16, 0, 0);
}

// ---------------------------------------------------------------------------
// Unified projection kernel. Slices (blockIdx.y>>3):
//   0: Q = relu(Wt.tgt + bt) * log2e  -> fp16 [b][n][64]   (fp32 VALU, exact)
//   1: K = relu(Wr.ref + br)          -> fp16 [b][n][64]   (fp32 VALU, exact)
//      + Vw = fp16(ref)               -> fp16 [b][128][n]  (free: same loads)
//   2: G = Wo.tgt + bo                -> fp32 [b][128][n]  (fp16 MFMA, fp32 acc)
// 128 tokens per block, 256 threads, grid (32, 24).
// ---------------------------------------------------------------------------
__global__ __launch_bounds__(256, 2) void proj_all2(
    const float* __restrict__ tgt, const float* __restrict__ ref,
    const float* __restrict__ Wt, const float* __restrict__ Wr,
    const float* __restrict__ Wo, const float* __restrict__ bt,
    const float* __restrict__ br, const float* __restrict__ bo,
    unsigned short* __restrict__ Qw, unsigned short* __restrict__ Kw,
    unsigned short* __restrict__ Vw, float* __restrict__ Gw)
{
    __shared__ __align__(16) unsigned char smem[128 * 65 * 4];   // 33280 B
    const int t = threadIdx.x;
    const int slice = blockIdx.y >> 3;
    const int b = blockIdx.y & 7;
    const int tokb = blockIdx.x << 7;          // 128 tokens / block

    if (slice < 2) {
        // ---------------- Q / K : exact fp32 VALU path ----------------
        float* ws = (float*)smem;              // W^T [c][oc], stride 65
        const float* X    = slice ? ref : tgt;
        const float* W    = slice ? Wr  : Wt;
        const float* bias = slice ? br  : bt;
        const float scale = slice ? 1.0f : kLog2e;

        #pragma unroll
        for (int k = 0; k < 32; ++k) {
            int i = t + k * 256;               // 0..8191
            int c = i & 127, oc = i >> 7;
            ws[c * 65 + oc] = W[(size_t)oc * kC + c] * scale;
        }
        __syncthreads();

        const int tokg = t >> 3;               // 0..31
        const int ocg  = t & 7;                // 0..7
        const int tok0 = tokb + tokg * 4;

        float bv[8];
        #pragma unroll
        for (int j = 0; j < 8; ++j) bv[j] = bias[ocg * 8 + j] * scale;
        float acc[4][8];
        #pragma unroll
        for (int i = 0; i < 4; ++i)
            #pragma unroll
            for (int j = 0; j < 8; ++j) acc[i][j] = bv[j];

        const float* Xb = X + ((size_t)b * kC) * kN + tok0;
        unsigned short* Vout = Vw + ((size_t)b * kC) * kN + tok0;

        #pragma unroll 4
        for (int c = 0; c < kC; ++c) {
            f32x4 x = *(const f32x4*)(Xb + (size_t)c * kN);
            if (slice == 1 && ocg == 0)        // fold V fp16 conversion in
                *(uint2*)(Vout + (size_t)c * kN) =
                    make_uint2(pkrtz(x[0], x[1]), pkrtz(x[2], x[3]));
            f32x4 w0 = *(const f32x4*)(ws + c * 65 + ocg * 8);
            f32x4 w1 = *(const f32x4*)(ws + c * 65 + ocg * 8 + 4);
            float ww[8] = {w0[0], w0[1], w0[2], w0[3], w1[0], w1[1], w1[2], w1[3]};
            #pragma unroll
            for (int i = 0; i < 4; ++i)
                #pragma unroll
                for (int j = 0; j < 8; ++j) acc[i][j] = fmaf(x[i], ww[j], acc[i][j]);
        }

        unsigned short* outp = slice ? Kw : Qw;
        #pragma unroll
        for (int i = 0; i < 4; ++i) {
            uint4 pk;
            pk.x = pkrtz(fmaxf(acc[i][0], 0.f), fmaxf(acc[i][1], 0.f));
            pk.y = pkrtz(fmaxf(acc[i][2], 0.f), fmaxf(acc[i][3], 0.f));
            pk.z = pkrtz(fmaxf(acc[i][4], 0.f), fmaxf(acc[i][5], 0.f));
            pk.w = pkrtz(fmaxf(acc[i][6], 0.f), fmaxf(acc[i][7], 0.f));
            *(uint4*)(outp + ((size_t)b * kN + tok0 + i) * kCH + ocg * 8) = pk;
        }
    } else {
        // ---------------- G : fp16 MFMA path ----------------
        unsigned short* Xs = (unsigned short*)smem;    // [128 tok][128 c] swizzled
        const float* Xb = tgt + ((size_t)b * kC) * kN + tokb;

        // stage fp32 [c][tok] -> fp16 LDS [tok][c], 16B chunk cc ^= (tok&7)
        const int tk4 = (t & 31) * 4;
        const int c8a = (t >> 5) * 8;
        #pragma unroll
        for (int half = 0; half < 2; ++half) {
            const int c8 = c8a + half * 64;
            f32x4 xv[8];
            #pragma unroll
            for (int j = 0; j < 8; ++j)
                xv[j] = *(const f32x4*)(Xb + (size_t)(c8 + j) * kN + tk4);
            #pragma unroll
            for (int tt = 0; tt < 4; ++tt) {
                const int s = (tt + t) & 3;            // rotate to spread banks
                const int tok = tk4 + s;
                const int cc = (c8 >> 3) ^ (tok & 7);
                uint4 pk;
                pk.x = pkrtz(xv[0][s], xv[1][s]);
                pk.y = pkrtz(xv[2][s], xv[3][s]);
                pk.z = pkrtz(xv[4][s], xv[5][s]);
                pk.w = pkrtz(xv[6][s], xv[7][s]);
                *(uint4*)(Xs + tok * 128 + cc * 8) = pk;
            }
        }
        __syncthreads();

        const int w = t >> 6, lane = t & 63;
        const int lg = (lane >> 4) & 3, lm = lane & 15;
        const int ocb = w * 32;                        // wave owns 32 oc

        f16x8 wf[2][4];
        float bvv[2][4];
        #pragma unroll
        for (int ot = 0; ot < 2; ++ot) {
            const int oc = ocb + ot * 16 + lm;
            #pragma unroll
            for (int ks = 0; ks < 4; ++ks) {
                const float* wp = Wo + (size_t)oc * kC + ks * 32 + lg * 8;
                f32x4 f0 = *(const f32x4*)wp;
                f32x4 f1 = *(const f32x4*)(wp + 4);
                union { f16x8 h; uint4 u; } cv;
                cv.u = make_uint4(pkrtz(f0[0], f0[1]), pkrtz(f0[2], f0[3]),
                                  pkrtz(f1[0], f1[1]), pkrtz(f1[2], f1[3]));
                wf[ot][ks] = cv.h;
            }
            #pragma unroll
            for (int r = 0; r < 4; ++r) bvv[ot][r] = bo[ocb + ot * 16 + lg * 4 + r];
        }

        float* Gb = Gw + ((size_t)b * kC) * kN + tokb;
        #pragma unroll
        for (int ns = 0; ns < 8; ++ns) {
            const int tok = ns * 16 + lm;
            f16x8 xf[4];
            #pragma unroll
            for (int ks = 0; ks < 4; ++ks)
                xf[ks] = *(const f16x8*)(Xs + tok * 128 +
                                         (((ks * 4 + lg) ^ (tok & 7)) << 3));
            #pragma unroll
            for (int ot = 0; ot < 2; ++ot) {
                f32x4 acc = {bvv[ot][0], bvv[ot][1], bvv[ot][2], bvv[ot][3]};
                #pragma unroll
                for (int ks = 0; ks < 4; ++ks)
                    acc = __builtin_amdgcn_mfma_f32_16x16x32_f16(wf[ot][ks], xf[ks], acc, 0, 0, 0);
                #pragma unroll
                for (int r = 0; r < 4; ++r)
                    Gb[(size_t)(ocb + ot * 16 + lg * 4 + r) * kN + tok] = acc[r];
            }
        }
    }
}

// ---------------------------------------------------------------------------
// Flash attention, fp16 MFMA 16x16x32, S^T = K.Q^T. LDS ping-pong, 1 barrier
// per 64-key tile. R7 deltas: K/V staged via global_load_lds (linear LDS dest,
// inverse-swizzled global src — same XOR involution as the fragment reads);
// row-sum l computed by MFMA against an all-ones B operand (exactly matches
// the fp16-rounded P numerator, no psum VALU, no epilogue shuffles); setprio
// around MFMA clusters.
// ---------------------------------------------------------------------------
__global__ __launch_bounds__(256, 2) void flash6_kernel(
    const unsigned short* __restrict__ Qw,   // [8][4096][64] fp16 (x log2e)
    const unsigned short* __restrict__ Kw,   // [8][4096][64] fp16
    const unsigned short* __restrict__ Vw,   // [8][128][4096] fp16
    const float* __restrict__ Gw,            // [8][128][4096] fp32 gate
    float* __restrict__ out)                 // [8][128][4096]
{
    __shared__ __align__(16) unsigned short Ks[2][64 * 64];
    __shared__ __align__(16) unsigned short Vs[2][128 * 64];
    __shared__ __align__(16) unsigned short Ps[64 * 64];

    const int t = threadIdx.x;
    const int b = blockIdx.x & 7;
    const int n0 = (blockIdx.x >> 3) << 6;
    const int w = t >> 6, lane = t & 63;
    const int lg = (lane >> 4) & 3, lm = lane & 15;
    const int row_q = w * 16 + lm;
    const int swz = lm & 7;

    const unsigned short* Qb = Qw + ((size_t)b * kN) * kCH;
    const unsigned short* Kb = Kw + ((size_t)b * kN) * kCH;
    const unsigned short* Vb = Vw + ((size_t)b * kC) * kN;

    f16x8 qf0 = *(const f16x8*)(Qb + (size_t)(n0 + row_q) * kCH + (lg << 3));
    f16x8 qf1 = *(const f16x8*)(Qb + (size_t)(n0 + row_q) * kCH + 32 + (lg << 3));

    // staging geometry: thread t owns 16B chunk (row = t>>3, col-chunk = t&7);
    // LDS dest is linear, global source column pre-swizzled by the same XOR.
    const int srow = t >> 3, scol = t & 7;
    const int sco  = (scol ^ (srow & 7)) << 3;
    const int wv   = t >> 6;                  // wave-uniform

    const int fswz0 = (lg ^ swz) << 3;
    const int fswz1 = ((4 | lg) ^ swz) << 3;
    int psw[4];
    #pragma unroll
    for (int mb = 0; mb < 4; ++mb)
        psw[mb] = row_q * 64 + (((2 * mb + (lg >> 1)) ^ swz) << 3) + ((lg & 1) << 2);

    union { f16x8 h; uint4 u; } onec;
    onec.u = make_uint4(0x3c003c00u, 0x3c003c00u, 0x3c003c00u, 0x3c003c00u);
    const f16x8 onev = onec.h;               // all fp16 1.0

    f32x4 O[8];
    #pragma unroll
    for (int cb = 0; cb < 8; ++cb) O[cb] = (f32x4){0.f, 0.f, 0.f, 0.f};
    f32x4 L = (f32x4){0.f, 0.f, 0.f, 0.f};   // per-row sum of fp16 P (MFMA)
    float m_run = 0.0f;                      // S >= 0 (relu inputs), exp2 domain

    auto stage = [&](int buf, int m0) {
        g2l16(Kb + (size_t)(m0 + srow) * kCH + sco,      Ks[buf] + wv * 512);
        g2l16(Kb + (size_t)(m0 + 32 + srow) * kCH + sco, Ks[buf] + 2048 + wv * 512);
        #pragma unroll
        for (int j = 0; j < 4; ++j)
            g2l16(Vb + (size_t)(32 * j + srow) * kN + m0 + sco,
                  Vs[buf] + j * 2048 + wv * 512);
    };
    stage(0, 0);                             // prologue: tile 0 -> buffer 0

    for (int kt = 0; kt < kN / 64; ++kt) {
        const int cur = kt & 1;
        __syncthreads();                     // drains vmcnt -> staged tile ready
        if (kt + 1 < kN / 64) stage(cur ^ 1, (kt + 1) << 6);

        // ---- QK^T -> S^T (log2 domain) ----
        f32x4 s[4];
        __builtin_amdgcn_s_setprio(1);
        #pragma unroll
        for (int mb = 0; mb < 4; ++mb) {
            const unsigned short* kr = Ks[cur] + ((mb * 16 + lm) << 6);
            f16x8 kf0 = *(const f16x8*)(kr + fswz0);
            f16x8 kf1 = *(const f16x8*)(kr + fswz1);
            f32x4 acc = (f32x4){0.f, 0.f, 0.f, 0.f};
            acc = __builtin_amdgcn_mfma_f32_16x16x32_f16(kf0, qf0, acc, 0, 0, 0);
            acc = __builtin_amdgcn_mfma_f32_16x16x32_f16(kf1, qf1, acc, 0, 0, 0);
            s[mb] = acc;
        }
        __builtin_amdgcn_s_setprio(0);

        // ---- online softmax (base 2), denominator via MFMA below ----
        float mloc = 0.0f;
        #pragma unroll
        for (int mb = 0; mb < 4; ++mb)
            #pragma unroll
            for (int r = 0; r < 4; ++r) mloc = fmaxf(mloc, s[mb][r]);
        mloc = fmaxf(mloc, __shfl_xor(mloc, 16, 64));
        mloc = fmaxf(mloc, __shfl_xor(mloc, 32, 64));
        const bool upd = __any(mloc > m_run);
        const float mnew = upd ? fmaxf(m_run, mloc) : m_run;

        #pragma unroll
        for (int mb = 0; mb < 4; ++mb) {
            unsigned plo = pkrtz(exp2f(s[mb][0] - mnew), exp2f(s[mb][1] - mnew));
            unsigned phi = pkrtz(exp2f(s[mb][2] - mnew), exp2f(s[mb][3] - mnew));
            *(uint2*)(Ps + psw[mb]) = make_uint2(plo, phi);
        }

        if (upd) {
            float alpha = exp2f(m_run - mnew);
            float a0 = __shfl(alpha, (lg << 2) + 0, 64);
            float a1 = __shfl(alpha, (lg << 2) + 1, 64);
            float a2 = __shfl(alpha, (lg << 2) + 2, 64);
            float a3 = __shfl(alpha, (lg << 2) + 3, 64);
            #pragma unroll
            for (int cb = 0; cb < 8; ++cb) {
                O[cb][0] *= a0; O[cb][1] *= a1; O[cb][2] *= a2; O[cb][3] *= a3;
            }
            L[0] *= a0; L[1] *= a1; L[2] *= a2; L[3] *= a3;
            m_run = mnew;
        }

        // ---- PV + row-sum (ones MFMA) ----
        f16x8 pf0 = *(const f16x8*)(Ps + row_q * 64 + fswz0);
        f16x8 pf1 = *(const f16x8*)(Ps + row_q * 64 + fswz1);
        __builtin_amdgcn_s_setprio(1);
        L = __builtin_amdgcn_mfma_f32_16x16x32_f16(pf0, onev, L, 0, 0, 0);
        L = __builtin_amdgcn_mfma_f32_16x16x32_f16(pf1, onev, L, 0, 0, 0);
        #pragma unroll
        for (int cb = 0; cb < 8; ++cb) {
            const unsigned short* vr = Vs[cur] + ((cb * 16 + lm) << 6);
            f16x8 vf0 = *(const f16x8*)(vr + fswz0);
            f16x8 vf1 = *(const f16x8*)(vr + fswz1);
            O[cb] = __builtin_amdgcn_mfma_f32_16x16x32_f16(pf0, vf0, O[cb], 0, 0, 0);
            O[cb] = __builtin_amdgcn_mfma_f32_16x16x32_f16(pf1, vf1, O[cb], 0, 0, 0);
        }
        __builtin_amdgcn_s_setprio(0);
    }

    // ---- epilogue: normalize (per-lane L), gate, store float4 ----
    const float i0 = 1.0f / L[0], i1 = 1.0f / L[1];
    const float i2 = 1.0f / L[2], i3 = 1.0f / L[3];
    const float* Gb = Gw + ((size_t)b * kC) * kN;
    float* Ob = out + ((size_t)b * kC) * kN;
    #pragma unroll
    for (int cb = 0; cb < 8; ++cb) {
        int c = cb * 16 + lm;
        size_t base = (size_t)c * kN + n0 + w * 16 + (lg << 2);
        float4 g = *(const float4*)(Gb + base);
        float4 res;
        res.x = O[cb][0] * i0 * g.x;
        res.y = O[cb][1] * i1 * g.y;
        res.z = O[cb][2] * i2 * g.z;
        res.w = O[cb][3] * i3 * g.w;
        *(float4*)(Ob + base) = res;
    }
}

// ---------------------------------------------------------------------------
extern "C" void kernel_launch(void* const* d_in, const int* in_sizes, int n_in,
                              void* d_out, int out_size, void* d_ws, size_t ws_size,
                              hipStream_t stream) {
    const float* tgt   = (const float*)d_in[0];
    const float* ref   = (const float*)d_in[1];
    const float* W_tgt = (const float*)d_in[2];
    const float* b_tgt = (const float*)d_in[3];
    const float* W_ref = (const float*)d_in[4];
    const float* b_ref = (const float*)d_in[5];
    const float* W_out = (const float*)d_in[6];
    const float* b_out = (const float*)d_in[7];
    float* out = (float*)d_out;

    const size_t QK = (size_t)8 * kN * kCH;              // fp16 -> 4 MB each
    const size_t CV = (size_t)8 * kC * kN;               // fp16 -> 8 MB
    unsigned short* Qw = (unsigned short*)d_ws;          // 4 MB
    unsigned short* Kw = Qw + QK;                        // 4 MB
    unsigned short* Vw = Kw + QK;                        // 8 MB
    float*          Gw = (float*)(Vw + CV);              // 16 MB (total 32 MB)

    proj_all2<<<dim3(32, 24), 256, 0, stream>>>(tgt, ref, W_tgt, W_ref, W_out,
                                                b_tgt, b_ref, b_out, Qw, Kw, Vw, Gw);
    flash6_kernel<<<dim3(512), 256, 0, stream>>>(Qw, Kw, Vw, Gw, out);
}

// Round 2
// 195.401 us; speedup vs baseline: 1.2360x; 1.2360x over previous
//
#include <hip/hip_runtime.h>

typedef __attribute__((ext_vector_type(8))) _Float16 f16x8;   // 8 fp16 = 4 VGPRs
typedef __attribute__((ext_vector_type(4))) float f32x4;

constexpr int kC  = 128;
constexpr int kCH = 64;
constexpr int kN  = 4096;
constexpr float kLog2e = 1.4426950408889634f;

__device__ __forceinline__ unsigned pkrtz(float a, float b) {
    union { __fp16 __attribute__((ext_vector_type(2))) v; unsigned u; } cv;
    cv.v = __builtin_amdgcn_cvt_pkrtz(a, b);
    return cv.u;
}

// direct global->LDS DMA, 16B per lane, dest = wave-uniform base + lane*16
__device__ __forceinline__ void g2l16(const unsigned short* g, unsigned short* l) {
    __builtin_amdgcn_global_load_lds(
        (const __attribute__((address_space(1))) unsigned int*)(g),
        (__attribute__((address_space(3))) unsigned int*)(l),
        16, 0, 0);
}

// ---------------------------------------------------------------------------
// All-MFMA projection. Slices (blockIdx.y>>3):
//   0: Q = relu(Wt.tgt + bt) * log2e  -> fp16 [b][n][64]
//   1: K = relu(Wr.ref + br)          -> fp16 [b][n][64]
//      + Vw = fp16(ref)               -> fp16 [b][128][n]  (written from the
//        staging registers -- the ref tile is already in VGPRs)
//   2: G = Wo.tgt + bo                -> fp32 [b][128][n]
// All via mfma_f32_16x16x32_f16 (fp32 accum). 128-token tiles, 256 threads,
// 32KB LDS, grid (32, 24) = 768 blocks = 3/CU.
// Staging uses STATIC vector-element indexing only (rule #20 fix vs R1).
// ---------------------------------------------------------------------------
__global__ __launch_bounds__(256, 3) void proj_mfma(
    const float* __restrict__ tgt, const float* __restrict__ ref,
    const float* __restrict__ Wt, const float* __restrict__ Wr,
    const float* __restrict__ Wo, const float* __restrict__ bt,
    const float* __restrict__ br, const float* __restrict__ bo,
    unsigned short* __restrict__ Qw, unsigned short* __restrict__ Kw,
    unsigned short* __restrict__ Vw, float* __restrict__ Gw)
{
    __shared__ __align__(16) unsigned short Xs[128 * 128];   // [tok][c] fp16, 32KB
    const int t = threadIdx.x;
    const int slice = blockIdx.y >> 3;       // 0=Q, 1=K(+V), 2=G
    const int b = blockIdx.y & 7;
    const int tokb = blockIdx.x << 7;

    const float* X = (slice == 1) ? ref : tgt;
    const float* Xb = X + ((size_t)b * kC) * kN + tokb;
    unsigned short* Vout = Vw + ((size_t)b * kC) * kN + tokb;

    // ---- stage fp32 [c][tok] -> fp16 LDS [tok][c], 16B chunk cc ^= (tok&7) ----
    const int tk4 = (t & 31) * 4;
    const int c8a = (t >> 5) * 8;
    #pragma unroll
    for (int half = 0; half < 2; ++half) {
        const int c8 = c8a + half * 64;
        f32x4 xv[8];
        #pragma unroll
        for (int j = 0; j < 8; ++j)
            xv[j] = *(const f32x4*)(Xb + (size_t)(c8 + j) * kN + tk4);
        if (slice == 1) {                    // fold V fp32->fp16 passthrough
            #pragma unroll
            for (int j = 0; j < 8; ++j)
                *(uint2*)(Vout + (size_t)(c8 + j) * kN + tk4) =
                    make_uint2(pkrtz(xv[j][0], xv[j][1]), pkrtz(xv[j][2], xv[j][3]));
        }
        #pragma unroll
        for (int s = 0; s < 4; ++s) {        // s STATIC: no runtime vec indexing
            const int tok = tk4 + s;
            const int cc = (c8 >> 3) ^ (tok & 7);
            uint4 pk;
            pk.x = pkrtz(xv[0][s], xv[1][s]);
            pk.y = pkrtz(xv[2][s], xv[3][s]);
            pk.z = pkrtz(xv[4][s], xv[5][s]);
            pk.w = pkrtz(xv[6][s], xv[7][s]);
            *(uint4*)(Xs + tok * 128 + cc * 8) = pk;
        }
    }
    __syncthreads();

    const int w = t >> 6, lane = t & 63;
    const int lg = (lane >> 4) & 3, lm = lane & 15;

    if (slice == 2) {
        // ---------------- G : 128 oc, fp32 [oc][tok] out ----------------
        const int ocb = w * 32;              // wave owns 32 oc
        f16x8 wf[2][4];
        float bvv[2][4];
        #pragma unroll
        for (int ot = 0; ot < 2; ++ot) {
            const int oc = ocb + ot * 16 + lm;
            #pragma unroll
            for (int ks = 0; ks < 4; ++ks) {
                const float* wp = Wo + (size_t)oc * kC + ks * 32 + lg * 8;
                f32x4 f0 = *(const f32x4*)wp;
                f32x4 f1 = *(const f32x4*)(wp + 4);
                union { f16x8 h; uint4 u; } cv;
                cv.u = make_uint4(pkrtz(f0[0], f0[1]), pkrtz(f0[2], f0[3]),
                                  pkrtz(f1[0], f1[1]), pkrtz(f1[2], f1[3]));
                wf[ot][ks] = cv.h;
            }
            #pragma unroll
            for (int r = 0; r < 4; ++r) bvv[ot][r] = bo[ocb + ot * 16 + lg * 4 + r];
        }

        float* Gb = Gw + ((size_t)b * kC) * kN + tokb;
        #pragma unroll
        for (int ns = 0; ns < 8; ++ns) {
            const int tok = ns * 16 + lm;
            f16x8 xf[4];
            #pragma unroll
            for (int ks = 0; ks < 4; ++ks)
                xf[ks] = *(const f16x8*)(Xs + tok * 128 +
                                         (((ks * 4 + lg) ^ (tok & 7)) << 3));
            #pragma unroll
            for (int ot = 0; ot < 2; ++ot) {
                f32x4 acc = {bvv[ot][0], bvv[ot][1], bvv[ot][2], bvv[ot][3]};
                #pragma unroll
                for (int ks = 0; ks < 4; ++ks)
                    acc = __builtin_amdgcn_mfma_f32_16x16x32_f16(wf[ot][ks], xf[ks], acc, 0, 0, 0);
                #pragma unroll
                for (int r = 0; r < 4; ++r)
                    Gb[(size_t)(ocb + ot * 16 + lg * 4 + r) * kN + tok] = acc[r];
            }
        }
    } else {
        // ---------------- Q / K : 64 oc, relu, fp16 [tok][oc] out ----------------
        const float* W    = slice ? Wr : Wt;
        const float* bias = slice ? br : bt;
        const float scale = slice ? 1.0f : kLog2e;
        const int ocb = w * 16;              // wave owns 16 oc

        f16x8 wf[4];
        #pragma unroll
        for (int ks = 0; ks < 4; ++ks) {
            const float* wp = W + (size_t)(ocb + lm) * kC + ks * 32 + lg * 8;
            f32x4 f0 = *(const f32x4*)wp;
            f32x4 f1 = *(const f32x4*)(wp + 4);
            union { f16x8 h; uint4 u; } cv;
            cv.u = make_uint4(pkrtz(f0[0] * scale, f0[1] * scale),
                              pkrtz(f0[2] * scale, f0[3] * scale),
                              pkrtz(f1[0] * scale, f1[1] * scale),
                              pkrtz(f1[2] * scale, f1[3] * scale));
            wf[ks] = cv.h;
        }
        float bv[4];
        #pragma unroll
        for (int r = 0; r < 4; ++r) bv[r] = bias[ocb + lg * 4 + r] * scale;

        unsigned short* outp = (slice ? Kw : Qw) + ((size_t)b * kN + tokb) * kCH;
        #pragma unroll
        for (int ns = 0; ns < 8; ++ns) {
            const int tok = ns * 16 + lm;
            f16x8 xf[4];
            #pragma unroll
            for (int ks = 0; ks < 4; ++ks)
                xf[ks] = *(const f16x8*)(Xs + tok * 128 +
                                         (((ks * 4 + lg) ^ (tok & 7)) << 3));
            f32x4 acc = {bv[0], bv[1], bv[2], bv[3]};
            #pragma unroll
            for (int ks = 0; ks < 4; ++ks)
                acc = __builtin_amdgcn_mfma_f32_16x16x32_f16(wf[ks], xf[ks], acc, 0, 0, 0);
            // D: row r -> oc = ocb+lg*4+r, col -> tok = ns*16+lm
            uint2 pk;
            pk.x = pkrtz(fmaxf(acc[0], 0.f), fmaxf(acc[1], 0.f));
            pk.y = pkrtz(fmaxf(acc[2], 0.f), fmaxf(acc[3], 0.f));
            *(uint2*)(outp + (size_t)tok * kCH + ocb + lg * 4) = pk;
        }
    }
}

// ---------------------------------------------------------------------------
// Flash attention, fp16 MFMA 16x16x32, S^T = K.Q^T. LDS ping-pong, 1 barrier
// per 64-key tile. Byte-identical to R1's flash6 (controlled baseline):
// global_load_lds staging, MFMA ones-row-sum for l, setprio around MFMA.
// ---------------------------------------------------------------------------
__global__ __launch_bounds__(256, 2) void flash6_kernel(
    const unsigned short* __restrict__ Qw,   // [8][4096][64] fp16 (x log2e)
    const unsigned short* __restrict__ Kw,   // [8][4096][64] fp16
    const unsigned short* __restrict__ Vw,   // [8][128][4096] fp16
    const float* __restrict__ Gw,            // [8][128][4096] fp32 gate
    float* __restrict__ out)                 // [8][128][4096]
{
    __shared__ __align__(16) unsigned short Ks[2][64 * 64];
    __shared__ __align__(16) unsigned short Vs[2][128 * 64];
    __shared__ __align__(16) unsigned short Ps[64 * 64];

    const int t = threadIdx.x;
    const int b = blockIdx.x & 7;
    const int n0 = (blockIdx.x >> 3) << 6;
    const int w = t >> 6, lane = t & 63;
    const int lg = (lane >> 4) & 3, lm = lane & 15;
    const int row_q = w * 16 + lm;
    const int swz = lm & 7;

    const unsigned short* Qb = Qw + ((size_t)b * kN) * kCH;
    const unsigned short* Kb = Kw + ((size_t)b * kN) * kCH;
    const unsigned short* Vb = Vw + ((size_t)b * kC) * kN;

    f16x8 qf0 = *(const f16x8*)(Qb + (size_t)(n0 + row_q) * kCH + (lg << 3));
    f16x8 qf1 = *(const f16x8*)(Qb + (size_t)(n0 + row_q) * kCH + 32 + (lg << 3));

    const int srow = t >> 3, scol = t & 7;
    const int sco  = (scol ^ (srow & 7)) << 3;
    const int wv   = t >> 6;

    const int fswz0 = (lg ^ swz) << 3;
    const int fswz1 = ((4 | lg) ^ swz) << 3;
    int psw[4];
    #pragma unroll
    for (int mb = 0; mb < 4; ++mb)
        psw[mb] = row_q * 64 + (((2 * mb + (lg >> 1)) ^ swz) << 3) + ((lg & 1) << 2);

    union { f16x8 h; uint4 u; } onec;
    onec.u = make_uint4(0x3c003c00u, 0x3c003c00u, 0x3c003c00u, 0x3c003c00u);
    const f16x8 onev = onec.h;               // all fp16 1.0

    f32x4 O[8];
    #pragma unroll
    for (int cb = 0; cb < 8; ++cb) O[cb] = (f32x4){0.f, 0.f, 0.f, 0.f};
    f32x4 L = (f32x4){0.f, 0.f, 0.f, 0.f};
    float m_run = 0.0f;

    auto stage = [&](int buf, int m0) {
        g2l16(Kb + (size_t)(m0 + srow) * kCH + sco,      Ks[buf] + wv * 512);
        g2l16(Kb + (size_t)(m0 + 32 + srow) * kCH + sco, Ks[buf] + 2048 + wv * 512);
        #pragma unroll
        for (int j = 0; j < 4; ++j)
            g2l16(Vb + (size_t)(32 * j + srow) * kN + m0 + sco,
                  Vs[buf] + j * 2048 + wv * 512);
    };
    stage(0, 0);

    for (int kt = 0; kt < kN / 64; ++kt) {
        const int cur = kt & 1;
        __syncthreads();
        if (kt + 1 < kN / 64) stage(cur ^ 1, (kt + 1) << 6);

        // ---- QK^T -> S^T (log2 domain) ----
        f32x4 s[4];
        __builtin_amdgcn_s_setprio(1);
        #pragma unroll
        for (int mb = 0; mb < 4; ++mb) {
            const unsigned short* kr = Ks[cur] + ((mb * 16 + lm) << 6);
            f16x8 kf0 = *(const f16x8*)(kr + fswz0);
            f16x8 kf1 = *(const f16x8*)(kr + fswz1);
            f32x4 acc = (f32x4){0.f, 0.f, 0.f, 0.f};
            acc = __builtin_amdgcn_mfma_f32_16x16x32_f16(kf0, qf0, acc, 0, 0, 0);
            acc = __builtin_amdgcn_mfma_f32_16x16x32_f16(kf1, qf1, acc, 0, 0, 0);
            s[mb] = acc;
        }
        __builtin_amdgcn_s_setprio(0);

        // ---- online softmax (base 2) ----
        float mloc = 0.0f;
        #pragma unroll
        for (int mb = 0; mb < 4; ++mb)
            #pragma unroll
            for (int r = 0; r < 4; ++r) mloc = fmaxf(mloc, s[mb][r]);
        mloc = fmaxf(mloc, __shfl_xor(mloc, 16, 64));
        mloc = fmaxf(mloc, __shfl_xor(mloc, 32, 64));
        const bool upd = __any(mloc > m_run);
        const float mnew = upd ? fmaxf(m_run, mloc) : m_run;

        #pragma unroll
        for (int mb = 0; mb < 4; ++mb) {
            unsigned plo = pkrtz(exp2f(s[mb][0] - mnew), exp2f(s[mb][1] - mnew));
            unsigned phi = pkrtz(exp2f(s[mb][2] - mnew), exp2f(s[mb][3] - mnew));
            *(uint2*)(Ps + psw[mb]) = make_uint2(plo, phi);
        }

        if (upd) {
            float alpha = exp2f(m_run - mnew);
            float a0 = __shfl(alpha, (lg << 2) + 0, 64);
            float a1 = __shfl(alpha, (lg << 2) + 1, 64);
            float a2 = __shfl(alpha, (lg << 2) + 2, 64);
            float a3 = __shfl(alpha, (lg << 2) + 3, 64);
            #pragma unroll
            for (int cb = 0; cb < 8; ++cb) {
                O[cb][0] *= a0; O[cb][1] *= a1; O[cb][2] *= a2; O[cb][3] *= a3;
            }
            L[0] *= a0; L[1] *= a1; L[2] *= a2; L[3] *= a3;
            m_run = mnew;
        }

        // ---- PV + row-sum (ones MFMA) ----
        f16x8 pf0 = *(const f16x8*)(Ps + row_q * 64 + fswz0);
        f16x8 pf1 = *(const f16x8*)(Ps + row_q * 64 + fswz1);
        __builtin_amdgcn_s_setprio(1);
        L = __builtin_amdgcn_mfma_f32_16x16x32_f16(pf0, onev, L, 0, 0, 0);
        L = __builtin_amdgcn_mfma_f32_16x16x32_f16(pf1, onev, L, 0, 0, 0);
        #pragma unroll
        for (int cb = 0; cb < 8; ++cb) {
            const unsigned short* vr = Vs[cur] + ((cb * 16 + lm) << 6);
            f16x8 vf0 = *(const f16x8*)(vr + fswz0);
            f16x8 vf1 = *(const f16x8*)(vr + fswz1);
            O[cb] = __builtin_amdgcn_mfma_f32_16x16x32_f16(pf0, vf0, O[cb], 0, 0, 0);
            O[cb] = __builtin_amdgcn_mfma_f32_16x16x32_f16(pf1, vf1, O[cb], 0, 0, 0);
        }
        __builtin_amdgcn_s_setprio(0);
    }

    // ---- epilogue: normalize (per-lane L), gate, store float4 ----
    const float i0 = 1.0f / L[0], i1 = 1.0f / L[1];
    const float i2 = 1.0f / L[2], i3 = 1.0f / L[3];
    const float* Gb = Gw + ((size_t)b * kC) * kN;
    float* Ob = out + ((size_t)b * kC) * kN;
    #pragma unroll
    for (int cb = 0; cb < 8; ++cb) {
        int c = cb * 16 + lm;
        size_t base = (size_t)c * kN + n0 + w * 16 + (lg << 2);
        float4 g = *(const float4*)(Gb + base);
        float4 res;
        res.x = O[cb][0] * i0 * g.x;
        res.y = O[cb][1] * i1 * g.y;
        res.z = O[cb][2] * i2 * g.z;
        res.w = O[cb][3] * i3 * g.w;
        *(float4*)(Ob + base) = res;
    }
}

// ---------------------------------------------------------------------------
extern "C" void kernel_launch(void* const* d_in, const int* in_sizes, int n_in,
                              void* d_out, int out_size, void* d_ws, size_t ws_size,
                              hipStream_t stream) {
    const float* tgt   = (const float*)d_in[0];
    const float* ref   = (const float*)d_in[1];
    const float* W_tgt = (const float*)d_in[2];
    const float* b_tgt = (const float*)d_in[3];
    const float* W_ref = (const float*)d_in[4];
    const float* b_ref = (const float*)d_in[5];
    const float* W_out = (const float*)d_in[6];
    const float* b_out = (const float*)d_in[7];
    float* out = (float*)d_out;

    const size_t QK = (size_t)8 * kN * kCH;              // fp16 -> 4 MB each
    const size_t CV = (size_t)8 * kC * kN;               // fp16 -> 8 MB
    unsigned short* Qw = (unsigned short*)d_ws;          // 4 MB
    unsigned short* Kw = Qw + QK;                        // 4 MB
    unsigned short* Vw = Kw + QK;                        // 8 MB
    float*          Gw = (float*)(Vw + CV);              // 16 MB (total 32 MB)

    proj_mfma<<<dim3(32, 24), 256, 0, stream>>>(tgt, ref, W_tgt, W_ref, W_out,
                                                b_tgt, b_ref, b_out, Qw, Kw, Vw, Gw);
    flash6_kernel<<<dim3(512), 256, 0, stream>>>(Qw, Kw, Vw, Gw, out);
}

// Round 3
// 186.758 us; speedup vs baseline: 1.2932x; 1.0463x over previous
//
#include <hip/hip_runtime.h>

typedef __attribute__((ext_vector_type(8))) _Float16 f16x8;   // 8 fp16 = 4 VGPRs
typedef __attribute__((ext_vector_type(4))) float f32x4;

constexpr int kC  = 128;
constexpr int kCH = 64;
constexpr int kN  = 4096;
constexpr float kLog2e = 1.4426950408889634f;

__device__ __forceinline__ unsigned pkrtz(float a, float b) {
    union { __fp16 __attribute__((ext_vector_type(2))) v; unsigned u; } cv;
    cv.v = __builtin_amdgcn_cvt_pkrtz(a, b);
    return cv.u;
}

__device__ __forceinline__ float x2(float x) {        // bare v_exp_f32
    return __builtin_amdgcn_exp2f(x);
}

// direct global->LDS DMA, 16B per lane, dest = wave-uniform base + lane*16
__device__ __forceinline__ void g2l16(const unsigned short* g, unsigned short* l) {
    __builtin_amdgcn_global_load_lds(
        (const __attribute__((address_space(1))) unsigned int*)(g),
        (__attribute__((address_space(3))) unsigned int*)(l),
        16, 0, 0);
}

// ---------------------------------------------------------------------------
// All-MFMA projection, 64-token tiles (R3: occupancy/latency fix).
// Slices (blockIdx.y>>3): 0=Q, 1=K(+V passthrough), 2=G.
// Grid (64, 24) = 1536 blocks, 16KB LDS, launch_bounds(256,4) -> ~4-5 blk/CU.
// W loads issued before the X-staging wait so the latency chains overlap.
// ---------------------------------------------------------------------------
__global__ __launch_bounds__(256, 4) void proj_mfma(
    const float* __restrict__ tgt, const float* __restrict__ ref,
    const float* __restrict__ Wt, const float* __restrict__ Wr,
    const float* __restrict__ Wo, const float* __restrict__ bt,
    const float* __restrict__ br, const float* __restrict__ bo,
    unsigned short* __restrict__ Qw, unsigned short* __restrict__ Kw,
    unsigned short* __restrict__ Vw, float* __restrict__ Gw)
{
    __shared__ __align__(16) unsigned short Xs[64 * 128];    // [tok][c] fp16, 16KB
    const int t = threadIdx.x;
    const int slice = blockIdx.y >> 3;       // 0=Q, 1=K(+V), 2=G
    const int b = blockIdx.y & 7;
    const int tokb = blockIdx.x << 6;        // 64 tokens / block

    const int w = t >> 6, lane = t & 63;
    const int lg = (lane >> 4) & 3, lm = lane & 15;

    const float* X = (slice == 1) ? ref : tgt;
    const float* Xb = X + ((size_t)b * kC) * kN + tokb;
    unsigned short* Vout = Vw + ((size_t)b * kC) * kN + tokb;

    // ---- issue X tile loads (8 strided f32x4 per thread) ----
    const int tk4 = (t & 15) * 4;            // token within tile
    const int c8  = (t >> 4) * 8;            // channel group
    f32x4 xv[8];
    #pragma unroll
    for (int j = 0; j < 8; ++j)
        xv[j] = *(const f32x4*)(Xb + (size_t)(c8 + j) * kN + tk4);

    // ---- W fragment loads + pack (overlaps X-load latency) ----
    f16x8 wf[2][4];
    float bvv[2][4];
    if (slice == 2) {
        const int ocb = w * 32;
        #pragma unroll
        for (int ot = 0; ot < 2; ++ot) {
            const int oc = ocb + ot * 16 + lm;
            #pragma unroll
            for (int ks = 0; ks < 4; ++ks) {
                const float* wp = Wo + (size_t)oc * kC + ks * 32 + lg * 8;
                f32x4 f0 = *(const f32x4*)wp;
                f32x4 f1 = *(const f32x4*)(wp + 4);
                union { f16x8 h; uint4 u; } cv;
                cv.u = make_uint4(pkrtz(f0[0], f0[1]), pkrtz(f0[2], f0[3]),
                                  pkrtz(f1[0], f1[1]), pkrtz(f1[2], f1[3]));
                wf[ot][ks] = cv.h;
            }
            #pragma unroll
            for (int r = 0; r < 4; ++r) bvv[ot][r] = bo[ocb + ot * 16 + lg * 4 + r];
        }
    } else {
        const float* W    = slice ? Wr : Wt;
        const float* bias = slice ? br : bt;
        const float scale = slice ? 1.0f : kLog2e;
        const int ocb = w * 16;
        #pragma unroll
        for (int ks = 0; ks < 4; ++ks) {
            const float* wp = W + (size_t)(ocb + lm) * kC + ks * 32 + lg * 8;
            f32x4 f0 = *(const f32x4*)wp;
            f32x4 f1 = *(const f32x4*)(wp + 4);
            union { f16x8 h; uint4 u; } cv;
            cv.u = make_uint4(pkrtz(f0[0] * scale, f0[1] * scale),
                              pkrtz(f0[2] * scale, f0[3] * scale),
                              pkrtz(f1[0] * scale, f1[1] * scale),
                              pkrtz(f1[2] * scale, f1[3] * scale));
            wf[0][ks] = cv.h;
        }
        #pragma unroll
        for (int r = 0; r < 4; ++r) bvv[0][r] = bias[ocb + lg * 4 + r] * scale;
    }

    // ---- V passthrough + LDS stage (fp16 [tok][c], chunk cc ^= tok&7) ----
    if (slice == 1) {
        #pragma unroll
        for (int j = 0; j < 8; ++j)
            *(uint2*)(Vout + (size_t)(c8 + j) * kN + tk4) =
                make_uint2(pkrtz(xv[j][0], xv[j][1]), pkrtz(xv[j][2], xv[j][3]));
    }
    #pragma unroll
    for (int s = 0; s < 4; ++s) {            // s STATIC (rule #20)
        const int tok = tk4 + s;
        const int cc = (c8 >> 3) ^ (tok & 7);
        uint4 pk;
        pk.x = pkrtz(xv[0][s], xv[1][s]);
        pk.y = pkrtz(xv[2][s], xv[3][s]);
        pk.z = pkrtz(xv[4][s], xv[5][s]);
        pk.w = pkrtz(xv[6][s], xv[7][s]);
        *(uint4*)(Xs + tok * 128 + cc * 8) = pk;
    }
    __syncthreads();

    if (slice == 2) {
        // ---------------- G : 128 oc, fp32 [oc][tok] out ----------------
        const int ocb = w * 32;
        float* Gb = Gw + ((size_t)b * kC) * kN + tokb;
        #pragma unroll
        for (int ns = 0; ns < 4; ++ns) {
            const int tok = ns * 16 + lm;
            f16x8 xf[4];
            #pragma unroll
            for (int ks = 0; ks < 4; ++ks)
                xf[ks] = *(const f16x8*)(Xs + tok * 128 +
                                         (((ks * 4 + lg) ^ (tok & 7)) << 3));
            #pragma unroll
            for (int ot = 0; ot < 2; ++ot) {
                f32x4 acc = {bvv[ot][0], bvv[ot][1], bvv[ot][2], bvv[ot][3]};
                #pragma unroll
                for (int ks = 0; ks < 4; ++ks)
                    acc = __builtin_amdgcn_mfma_f32_16x16x32_f16(wf[ot][ks], xf[ks], acc, 0, 0, 0);
                #pragma unroll
                for (int r = 0; r < 4; ++r)
                    Gb[(size_t)(ocb + ot * 16 + lg * 4 + r) * kN + tok] = acc[r];
            }
        }
    } else {
        // ------------- Q / K : 64 oc, relu, fp16 [tok][oc] out -------------
        const int ocb = w * 16;
        unsigned short* outp = (slice ? Kw : Qw) + ((size_t)b * kN + tokb) * kCH;
        #pragma unroll
        for (int ns = 0; ns < 4; ++ns) {
            const int tok = ns * 16 + lm;
            f16x8 xf[4];
            #pragma unroll
            for (int ks = 0; ks < 4; ++ks)
                xf[ks] = *(const f16x8*)(Xs + tok * 128 +
                                         (((ks * 4 + lg) ^ (tok & 7)) << 3));
            f32x4 acc = {bvv[0][0], bvv[0][1], bvv[0][2], bvv[0][3]};
            #pragma unroll
            for (int ks = 0; ks < 4; ++ks)
                acc = __builtin_amdgcn_mfma_f32_16x16x32_f16(wf[0][ks], xf[ks], acc, 0, 0, 0);
            uint2 pk;
            pk.x = pkrtz(fmaxf(acc[0], 0.f), fmaxf(acc[1], 0.f));
            pk.y = pkrtz(fmaxf(acc[2], 0.f), fmaxf(acc[3], 0.f));
            *(uint2*)(outp + (size_t)tok * kCH + ocb + lg * 4) = pk;
        }
    }
}

// ---------------------------------------------------------------------------
// Flash attention, fp16 MFMA 16x16x32, S^T = K.Q^T. LDS ping-pong, 1 barrier
// per 64-key tile. R3 deltas vs R2's flash6 (structure otherwise identical):
//   - exp2f -> __builtin_amdgcn_exp2f (bare v_exp_f32, no ocml guard code)
//   - kt unrolled by 2: ping/pong buffer pointers are loop-invariant, killing
//     per-access cndmask/address recompute on Ks[cur]/Vs[cur].
// ---------------------------------------------------------------------------
__global__ __launch_bounds__(256, 2) void flash7_kernel(
    const unsigned short* __restrict__ Qw,   // [8][4096][64] fp16 (x log2e)
    const unsigned short* __restrict__ Kw,   // [8][4096][64] fp16
    const unsigned short* __restrict__ Vw,   // [8][128][4096] fp16
    const float* __restrict__ Gw,            // [8][128][4096] fp32 gate
    float* __restrict__ out)                 // [8][128][4096]
{
    __shared__ __align__(16) unsigned short Ks[2][64 * 64];
    __shared__ __align__(16) unsigned short Vs[2][128 * 64];
    __shared__ __align__(16) unsigned short Ps[64 * 64];

    const int t = threadIdx.x;
    const int b = blockIdx.x & 7;
    const int n0 = (blockIdx.x >> 3) << 6;
    const int w = t >> 6, lane = t & 63;
    const int lg = (lane >> 4) & 3, lm = lane & 15;
    const int row_q = w * 16 + lm;
    const int swz = lm & 7;

    const unsigned short* Qb = Qw + ((size_t)b * kN) * kCH;
    const unsigned short* Kb = Kw + ((size_t)b * kN) * kCH;
    const unsigned short* Vb = Vw + ((size_t)b * kC) * kN;

    f16x8 qf0 = *(const f16x8*)(Qb + (size_t)(n0 + row_q) * kCH + (lg << 3));
    f16x8 qf1 = *(const f16x8*)(Qb + (size_t)(n0 + row_q) * kCH + 32 + (lg << 3));

    const int srow = t >> 3, scol = t & 7;
    const int sco  = (scol ^ (srow & 7)) << 3;
    const int wv   = t >> 6;

    const int fswz0 = (lg ^ swz) << 3;
    const int fswz1 = ((4 | lg) ^ swz) << 3;
    int psw[4];
    #pragma unroll
    for (int mb = 0; mb < 4; ++mb)
        psw[mb] = row_q * 64 + (((2 * mb + (lg >> 1)) ^ swz) << 3) + ((lg & 1) << 2);

    union { f16x8 h; uint4 u; } onec;
    onec.u = make_uint4(0x3c003c00u, 0x3c003c00u, 0x3c003c00u, 0x3c003c00u);
    const f16x8 onev = onec.h;               // all fp16 1.0

    f32x4 O[8];
    #pragma unroll
    for (int cb = 0; cb < 8; ++cb) O[cb] = (f32x4){0.f, 0.f, 0.f, 0.f};
    f32x4 L = (f32x4){0.f, 0.f, 0.f, 0.f};
    float m_run = 0.0f;

    unsigned short* Ks0 = Ks[0]; unsigned short* Ks1 = Ks[1];
    unsigned short* Vs0 = Vs[0]; unsigned short* Vs1 = Vs[1];

    auto stage = [&](unsigned short* Kd, unsigned short* Vd, int m0) {
        g2l16(Kb + (size_t)(m0 + srow) * kCH + sco,      Kd + wv * 512);
        g2l16(Kb + (size_t)(m0 + 32 + srow) * kCH + sco, Kd + 2048 + wv * 512);
        #pragma unroll
        for (int j = 0; j < 4; ++j)
            g2l16(Vb + (size_t)(32 * j + srow) * kN + m0 + sco,
                  Vd + j * 2048 + wv * 512);
    };
    stage(Ks0, Vs0, 0);                      // prologue: tile 0 -> buffer 0

    auto tile = [&](const unsigned short* Kc, const unsigned short* Vc,
                    unsigned short* Kn, unsigned short* Vn, int kt) {
        __syncthreads();                     // drains vmcnt -> staged tile ready
        if (kt + 1 < kN / 64) stage(Kn, Vn, (kt + 1) << 6);

        // ---- QK^T -> S^T (log2 domain) ----
        f32x4 s[4];
        __builtin_amdgcn_s_setprio(1);
        #pragma unroll
        for (int mb = 0; mb < 4; ++mb) {
            const unsigned short* kr = Kc + ((mb * 16 + lm) << 6);
            f16x8 kf0 = *(const f16x8*)(kr + fswz0);
            f16x8 kf1 = *(const f16x8*)(kr + fswz1);
            f32x4 acc = (f32x4){0.f, 0.f, 0.f, 0.f};
            acc = __builtin_amdgcn_mfma_f32_16x16x32_f16(kf0, qf0, acc, 0, 0, 0);
            acc = __builtin_amdgcn_mfma_f32_16x16x32_f16(kf1, qf1, acc, 0, 0, 0);
            s[mb] = acc;
        }
        __builtin_amdgcn_s_setprio(0);

        // ---- online softmax (base 2) ----
        float mloc = 0.0f;
        #pragma unroll
        for (int mb = 0; mb < 4; ++mb)
            #pragma unroll
            for (int r = 0; r < 4; ++r) mloc = fmaxf(mloc, s[mb][r]);
        mloc = fmaxf(mloc, __shfl_xor(mloc, 16, 64));
        mloc = fmaxf(mloc, __shfl_xor(mloc, 32, 64));
        const bool upd = __any(mloc > m_run);
        const float mnew = upd ? fmaxf(m_run, mloc) : m_run;

        #pragma unroll
        for (int mb = 0; mb < 4; ++mb) {
            unsigned plo = pkrtz(x2(s[mb][0] - mnew), x2(s[mb][1] - mnew));
            unsigned phi = pkrtz(x2(s[mb][2] - mnew), x2(s[mb][3] - mnew));
            *(uint2*)(Ps + psw[mb]) = make_uint2(plo, phi);
        }

        if (upd) {
            float alpha = x2(m_run - mnew);
            float a0 = __shfl(alpha, (lg << 2) + 0, 64);
            float a1 = __shfl(alpha, (lg << 2) + 1, 64);
            float a2 = __shfl(alpha, (lg << 2) + 2, 64);
            float a3 = __shfl(alpha, (lg << 2) + 3, 64);
            #pragma unroll
            for (int cb = 0; cb < 8; ++cb) {
                O[cb][0] *= a0; O[cb][1] *= a1; O[cb][2] *= a2; O[cb][3] *= a3;
            }
            L[0] *= a0; L[1] *= a1; L[2] *= a2; L[3] *= a3;
            m_run = mnew;
        }

        // ---- PV + row-sum (ones MFMA) ----
        f16x8 pf0 = *(const f16x8*)(Ps + row_q * 64 + fswz0);
        f16x8 pf1 = *(const f16x8*)(Ps + row_q * 64 + fswz1);
        __builtin_amdgcn_s_setprio(1);
        L = __builtin_amdgcn_mfma_f32_16x16x32_f16(pf0, onev, L, 0, 0, 0);
        L = __builtin_amdgcn_mfma_f32_16x16x32_f16(pf1, onev, L, 0, 0, 0);
        #pragma unroll
        for (int cb = 0; cb < 8; ++cb) {
            const unsigned short* vr = Vc + ((cb * 16 + lm) << 6);
            f16x8 vf0 = *(const f16x8*)(vr + fswz0);
            f16x8 vf1 = *(const f16x8*)(vr + fswz1);
            O[cb] = __builtin_amdgcn_mfma_f32_16x16x32_f16(pf0, vf0, O[cb], 0, 0, 0);
            O[cb] = __builtin_amdgcn_mfma_f32_16x16x32_f16(pf1, vf1, O[cb], 0, 0, 0);
        }
        __builtin_amdgcn_s_setprio(0);
    };

    for (int kt = 0; kt < kN / 64; kt += 2) {
        tile(Ks0, Vs0, Ks1, Vs1, kt);        // even: compute buf0, stage buf1
        tile(Ks1, Vs1, Ks0, Vs0, kt + 1);    // odd : compute buf1, stage buf0
    }

    // ---- epilogue: normalize (per-lane L), gate, store float4 ----
    const float i0 = 1.0f / L[0], i1 = 1.0f / L[1];
    const float i2 = 1.0f / L[2], i3 = 1.0f / L[3];
    const float* Gb = Gw + ((size_t)b * kC) * kN;
    float* Ob = out + ((size_t)b * kC) * kN;
    #pragma unroll
    for (int cb = 0; cb < 8; ++cb) {
        int c = cb * 16 + lm;
        size_t base = (size_t)c * kN + n0 + w * 16 + (lg << 2);
        float4 g = *(const float4*)(Gb + base);
        float4 res;
        res.x = O[cb][0] * i0 * g.x;
        res.y = O[cb][1] * i1 * g.y;
        res.z = O[cb][2] * i2 * g.z;
        res.w = O[cb][3] * i3 * g.w;
        *(float4*)(Ob + base) = res;
    }
}

// ---------------------------------------------------------------------------
extern "C" void kernel_launch(void* const* d_in, const int* in_sizes, int n_in,
                              void* d_out, int out_size, void* d_ws, size_t ws_size,
                              hipStream_t stream) {
    const float* tgt   = (const float*)d_in[0];
    const float* ref   = (const float*)d_in[1];
    const float* W_tgt = (const float*)d_in[2];
    const float* b_tgt = (const float*)d_in[3];
    const float* W_ref = (const float*)d_in[4];
    const float* b_ref = (const float*)d_in[5];
    const float* W_out = (const float*)d_in[6];
    const float* b_out = (const float*)d_in[7];
    float* out = (float*)d_out;

    const size_t QK = (size_t)8 * kN * kCH;              // fp16 -> 4 MB each
    const size_t CV = (size_t)8 * kC * kN;               // fp16 -> 8 MB
    unsigned short* Qw = (unsigned short*)d_ws;          // 4 MB
    unsigned short* Kw = Qw + QK;                        // 4 MB
    unsigned short* Vw = Kw + QK;                        // 8 MB
    float*          Gw = (float*)(Vw + CV);              // 16 MB (total 32 MB)

    proj_mfma<<<dim3(64, 24), 256, 0, stream>>>(tgt, ref, W_tgt, W_ref, W_out,
                                                b_tgt, b_ref, b_out, Qw, Kw, Vw, Gw);
    flash7_kernel<<<dim3(512), 256, 0, stream>>>(Qw, Kw, Vw, Gw, out);
}

// Round 4
// 183.431 us; speedup vs baseline: 1.3167x; 1.0181x over previous
//
#include <hip/hip_runtime.h>

typedef __attribute__((ext_vector_type(8))) _Float16 f16x8;   // 8 fp16 = 4 VGPRs
typedef __attribute__((ext_vector_type(4))) float f32x4;

constexpr int kC  = 128;
constexpr int kCH = 64;
constexpr int kN  = 4096;
constexpr float kLog2e = 1.4426950408889634f;

__device__ __forceinline__ unsigned pkrtz(float a, float b) {
    union { __fp16 __attribute__((ext_vector_type(2))) v; unsigned u; } cv;
    cv.v = __builtin_amdgcn_cvt_pkrtz(a, b);
    return cv.u;
}

__device__ __forceinline__ float x2(float x) {        // bare v_exp_f32
    return __builtin_amdgcn_exp2f(x);
}

// direct global->LDS DMA, 16B per lane, dest = wave-uniform base + lane*16
__device__ __forceinline__ void g2l16(const unsigned short* g, unsigned short* l) {
    __builtin_amdgcn_global_load_lds(
        (const __attribute__((address_space(1))) unsigned int*)(g),
        (__attribute__((address_space(3))) unsigned int*)(l),
        16, 0, 0);
}

// ---------------------------------------------------------------------------
// Fused projection (R4). Two slices (blockIdx.y>>3):
//   0: tgt -> Q = relu(Wt.tgt+bt)*log2e  AND  G = Wo.tgt+bo   (shared X tile)
//   1: ref -> K = relu(Wr.ref+br)        AND  V = fp16(ref) passthrough
// Each block: 2 token-tiles of 64, register-prefetched + LDS double-buffered
// (one barrier per tile; tile-1 loads issue before tile-0 compute and hide
// under it). Grid (32,16) = 512 blocks, 256 thr, 32KB LDS.
// ---------------------------------------------------------------------------
__global__ __launch_bounds__(256, 2) void proj_fused(
    const float* __restrict__ tgt, const float* __restrict__ ref,
    const float* __restrict__ Wt, const float* __restrict__ Wr,
    const float* __restrict__ Wo, const float* __restrict__ bt,
    const float* __restrict__ br, const float* __restrict__ bo,
    unsigned short* __restrict__ Qw, unsigned short* __restrict__ Kw,
    unsigned short* __restrict__ Vw, float* __restrict__ Gw)
{
    __shared__ __align__(16) unsigned short Xs[2][64 * 128];   // 2 x 16KB
    const int t = threadIdx.x;
    const int sl2 = blockIdx.y >> 3;         // 0 = tgt (Q+G), 1 = ref (K+V)
    const int b = blockIdx.y & 7;
    const int tok0 = blockIdx.x << 7;        // 128 tokens per block (2 tiles)

    const int w = t >> 6, lane = t & 63;
    const int lg = (lane >> 4) & 3, lm = lane & 15;

    const float* X = sl2 ? ref : tgt;
    const float* Xb0 = X + ((size_t)b * kC) * kN + tok0;
    unsigned short* Vout = Vw + ((size_t)b * kC) * kN + tok0;

    // ---- W fragments (loaded once per block; overlap with X loads) ----
    const float* Wqk  = sl2 ? Wr : Wt;
    const float* bqk  = sl2 ? br : bt;
    const float scale = sl2 ? 1.0f : kLog2e;

    f16x8 wfq[4];
    float bq[4];
    {
        const int ocb = w * 16;
        #pragma unroll
        for (int ks = 0; ks < 4; ++ks) {
            const float* wp = Wqk + (size_t)(ocb + lm) * kC + ks * 32 + lg * 8;
            f32x4 f0 = *(const f32x4*)wp;
            f32x4 f1 = *(const f32x4*)(wp + 4);
            union { f16x8 h; uint4 u; } cv;
            cv.u = make_uint4(pkrtz(f0[0] * scale, f0[1] * scale),
                              pkrtz(f0[2] * scale, f0[3] * scale),
                              pkrtz(f1[0] * scale, f1[1] * scale),
                              pkrtz(f1[2] * scale, f1[3] * scale));
            wfq[ks] = cv.h;
        }
        #pragma unroll
        for (int r = 0; r < 4; ++r) bq[r] = bqk[ocb + lg * 4 + r] * scale;
    }

    f16x8 wfg[2][4];
    float bg[2][4];
    if (sl2 == 0) {
        const int ocb = w * 32;
        #pragma unroll
        for (int ot = 0; ot < 2; ++ot) {
            const int oc = ocb + ot * 16 + lm;
            #pragma unroll
            for (int ks = 0; ks < 4; ++ks) {
                const float* wp = Wo + (size_t)oc * kC + ks * 32 + lg * 8;
                f32x4 f0 = *(const f32x4*)wp;
                f32x4 f1 = *(const f32x4*)(wp + 4);
                union { f16x8 h; uint4 u; } cv;
                cv.u = make_uint4(pkrtz(f0[0], f0[1]), pkrtz(f0[2], f0[3]),
                                  pkrtz(f1[0], f1[1]), pkrtz(f1[2], f1[3]));
                wfg[ot][ks] = cv.h;
            }
            #pragma unroll
            for (int r = 0; r < 4; ++r) bg[ot][r] = bo[ocb + ot * 16 + lg * 4 + r];
        }
    }

    const int tk4 = (t & 15) * 4;            // token within tile
    const int c8  = (t >> 4) * 8;            // channel group

    // ---- helpers (compile-time expanded; static vector indexing only) ----
    auto loadX = [&](int toff, f32x4* xv) {
        #pragma unroll
        for (int j = 0; j < 8; ++j)
            xv[j] = *(const f32x4*)(Xb0 + (size_t)(c8 + j) * kN + toff + tk4);
    };
    auto stageX = [&](const f32x4* xv, unsigned short* Xsb, int toff) {
        if (sl2 == 1) {                      // V fp16 passthrough (ref slice)
            #pragma unroll
            for (int j = 0; j < 8; ++j)
                *(uint2*)(Vout + (size_t)(c8 + j) * kN + toff + tk4) =
                    make_uint2(pkrtz(xv[j][0], xv[j][1]), pkrtz(xv[j][2], xv[j][3]));
        }
        #pragma unroll
        for (int s = 0; s < 4; ++s) {        // s STATIC (rule #20)
            const int tok = tk4 + s;
            const int cc = (c8 >> 3) ^ (tok & 7);
            uint4 pk;
            pk.x = pkrtz(xv[0][s], xv[1][s]);
            pk.y = pkrtz(xv[2][s], xv[3][s]);
            pk.z = pkrtz(xv[4][s], xv[5][s]);
            pk.w = pkrtz(xv[6][s], xv[7][s]);
            *(uint4*)(Xsb + tok * 128 + cc * 8) = pk;
        }
    };
    auto compute = [&](const unsigned short* Xsb, int tokb) {
        unsigned short* outp = (sl2 ? Kw : Qw) + ((size_t)b * kN + tokb) * kCH;
        float* Gb = Gw + ((size_t)b * kC) * kN + tokb;
        const int ocq = w * 16;
        const int ocg = w * 32;
        #pragma unroll
        for (int ns = 0; ns < 4; ++ns) {
            const int tok = ns * 16 + lm;
            f16x8 xf[4];
            #pragma unroll
            for (int ks = 0; ks < 4; ++ks)
                xf[ks] = *(const f16x8*)(Xsb + tok * 128 +
                                         (((ks * 4 + lg) ^ (tok & 7)) << 3));
            // ---- Q / K: 64 oc, relu, fp16 [tok][oc] ----
            {
                f32x4 acc = {bq[0], bq[1], bq[2], bq[3]};
                #pragma unroll
                for (int ks = 0; ks < 4; ++ks)
                    acc = __builtin_amdgcn_mfma_f32_16x16x32_f16(wfq[ks], xf[ks], acc, 0, 0, 0);
                uint2 pk;
                pk.x = pkrtz(fmaxf(acc[0], 0.f), fmaxf(acc[1], 0.f));
                pk.y = pkrtz(fmaxf(acc[2], 0.f), fmaxf(acc[3], 0.f));
                *(uint2*)(outp + (size_t)tok * kCH + ocq + lg * 4) = pk;
            }
            // ---- G: 128 oc, fp32 [oc][tok] (tgt slice only) ----
            if (sl2 == 0) {
                #pragma unroll
                for (int ot = 0; ot < 2; ++ot) {
                    f32x4 acc = {bg[ot][0], bg[ot][1], bg[ot][2], bg[ot][3]};
                    #pragma unroll
                    for (int ks = 0; ks < 4; ++ks)
                        acc = __builtin_amdgcn_mfma_f32_16x16x32_f16(wfg[ot][ks], xf[ks], acc, 0, 0, 0);
                    #pragma unroll
                    for (int r = 0; r < 4; ++r)
                        Gb[(size_t)(ocg + ot * 16 + lg * 4 + r) * kN + tok] = acc[r];
                }
            }
        }
    };

    // ---- pipeline: tile0 load+stage | barrier | tile1 load, tile0 compute,
    //      tile1 stage | barrier | tile1 compute ----
    f32x4 xv[8], xw[8];
    loadX(0, xv);
    stageX(xv, Xs[0], 0);
    __syncthreads();
    loadX(64, xw);                           // prefetch: hides under compute 0
    compute(Xs[0], tok0);
    stageX(xw, Xs[1], 64);
    __syncthreads();
    compute(Xs[1], tok0 + 64);
}

// ---------------------------------------------------------------------------
// Flash attention, fp16 MFMA 16x16x32, S^T = K.Q^T. LDS ping-pong, 1 barrier
// per 64-key tile. Byte-identical to R3's flash7 (controlled baseline):
// global_load_lds staging, bare v_exp_f32, static ping/pong via 2x unroll,
// MFMA ones-row-sum for l, setprio around MFMA.
// ---------------------------------------------------------------------------
__global__ __launch_bounds__(256, 2) void flash7_kernel(
    const unsigned short* __restrict__ Qw,   // [8][4096][64] fp16 (x log2e)
    const unsigned short* __restrict__ Kw,   // [8][4096][64] fp16
    const unsigned short* __restrict__ Vw,   // [8][128][4096] fp16
    const float* __restrict__ Gw,            // [8][128][4096] fp32 gate
    float* __restrict__ out)                 // [8][128][4096]
{
    __shared__ __align__(16) unsigned short Ks[2][64 * 64];
    __shared__ __align__(16) unsigned short Vs[2][128 * 64];
    __shared__ __align__(16) unsigned short Ps[64 * 64];

    const int t = threadIdx.x;
    const int b = blockIdx.x & 7;
    const int n0 = (blockIdx.x >> 3) << 6;
    const int w = t >> 6, lane = t & 63;
    const int lg = (lane >> 4) & 3, lm = lane & 15;
    const int row_q = w * 16 + lm;
    const int swz = lm & 7;

    const unsigned short* Qb = Qw + ((size_t)b * kN) * kCH;
    const unsigned short* Kb = Kw + ((size_t)b * kN) * kCH;
    const unsigned short* Vb = Vw + ((size_t)b * kC) * kN;

    f16x8 qf0 = *(const f16x8*)(Qb + (size_t)(n0 + row_q) * kCH + (lg << 3));
    f16x8 qf1 = *(const f16x8*)(Qb + (size_t)(n0 + row_q) * kCH + 32 + (lg << 3));

    const int srow = t >> 3, scol = t & 7;
    const int sco  = (scol ^ (srow & 7)) << 3;
    const int wv   = t >> 6;

    const int fswz0 = (lg ^ swz) << 3;
    const int fswz1 = ((4 | lg) ^ swz) << 3;
    int psw[4];
    #pragma unroll
    for (int mb = 0; mb < 4; ++mb)
        psw[mb] = row_q * 64 + (((2 * mb + (lg >> 1)) ^ swz) << 3) + ((lg & 1) << 2);

    union { f16x8 h; uint4 u; } onec;
    onec.u = make_uint4(0x3c003c00u, 0x3c003c00u, 0x3c003c00u, 0x3c003c00u);
    const f16x8 onev = onec.h;               // all fp16 1.0

    f32x4 O[8];
    #pragma unroll
    for (int cb = 0; cb < 8; ++cb) O[cb] = (f32x4){0.f, 0.f, 0.f, 0.f};
    f32x4 L = (f32x4){0.f, 0.f, 0.f, 0.f};
    float m_run = 0.0f;

    unsigned short* Ks0 = Ks[0]; unsigned short* Ks1 = Ks[1];
    unsigned short* Vs0 = Vs[0]; unsigned short* Vs1 = Vs[1];

    auto stage = [&](unsigned short* Kd, unsigned short* Vd, int m0) {
        g2l16(Kb + (size_t)(m0 + srow) * kCH + sco,      Kd + wv * 512);
        g2l16(Kb + (size_t)(m0 + 32 + srow) * kCH + sco, Kd + 2048 + wv * 512);
        #pragma unroll
        for (int j = 0; j < 4; ++j)
            g2l16(Vb + (size_t)(32 * j + srow) * kN + m0 + sco,
                  Vd + j * 2048 + wv * 512);
    };
    stage(Ks0, Vs0, 0);                      // prologue: tile 0 -> buffer 0

    auto tile = [&](const unsigned short* Kc, const unsigned short* Vc,
                    unsigned short* Kn, unsigned short* Vn, int kt) {
        __syncthreads();                     // drains vmcnt -> staged tile ready
        if (kt + 1 < kN / 64) stage(Kn, Vn, (kt + 1) << 6);

        // ---- QK^T -> S^T (log2 domain) ----
        f32x4 s[4];
        __builtin_amdgcn_s_setprio(1);
        #pragma unroll
        for (int mb = 0; mb < 4; ++mb) {
            const unsigned short* kr = Kc + ((mb * 16 + lm) << 6);
            f16x8 kf0 = *(const f16x8*)(kr + fswz0);
            f16x8 kf1 = *(const f16x8*)(kr + fswz1);
            f32x4 acc = (f32x4){0.f, 0.f, 0.f, 0.f};
            acc = __builtin_amdgcn_mfma_f32_16x16x32_f16(kf0, qf0, acc, 0, 0, 0);
            acc = __builtin_amdgcn_mfma_f32_16x16x32_f16(kf1, qf1, acc, 0, 0, 0);
            s[mb] = acc;
        }
        __builtin_amdgcn_s_setprio(0);

        // ---- online softmax (base 2) ----
        float mloc = 0.0f;
        #pragma unroll
        for (int mb = 0; mb < 4; ++mb)
            #pragma unroll
            for (int r = 0; r < 4; ++r) mloc = fmaxf(mloc, s[mb][r]);
        mloc = fmaxf(mloc, __shfl_xor(mloc, 16, 64));
        mloc = fmaxf(mloc, __shfl_xor(mloc, 32, 64));
        const bool upd = __any(mloc > m_run);
        const float mnew = upd ? fmaxf(m_run, mloc) : m_run;

        #pragma unroll
        for (int mb = 0; mb < 4; ++mb) {
            unsigned plo = pkrtz(x2(s[mb][0] - mnew), x2(s[mb][1] - mnew));
            unsigned phi = pkrtz(x2(s[mb][2] - mnew), x2(s[mb][3] - mnew));
            *(uint2*)(Ps + psw[mb]) = make_uint2(plo, phi);
        }

        if (upd) {
            float alpha = x2(m_run - mnew);
            float a0 = __shfl(alpha, (lg << 2) + 0, 64);
            float a1 = __shfl(alpha, (lg << 2) + 1, 64);
            float a2 = __shfl(alpha, (lg << 2) + 2, 64);
            float a3 = __shfl(alpha, (lg << 2) + 3, 64);
            #pragma unroll
            for (int cb = 0; cb < 8; ++cb) {
                O[cb][0] *= a0; O[cb][1] *= a1; O[cb][2] *= a2; O[cb][3] *= a3;
            }
            L[0] *= a0; L[1] *= a1; L[2] *= a2; L[3] *= a3;
            m_run = mnew;
        }

        // ---- PV + row-sum (ones MFMA) ----
        f16x8 pf0 = *(const f16x8*)(Ps + row_q * 64 + fswz0);
        f16x8 pf1 = *(const f16x8*)(Ps + row_q * 64 + fswz1);
        __builtin_amdgcn_s_setprio(1);
        L = __builtin_amdgcn_mfma_f32_16x16x32_f16(pf0, onev, L, 0, 0, 0);
        L = __builtin_amdgcn_mfma_f32_16x16x32_f16(pf1, onev, L, 0, 0, 0);
        #pragma unroll
        for (int cb = 0; cb < 8; ++cb) {
            const unsigned short* vr = Vc + ((cb * 16 + lm) << 6);
            f16x8 vf0 = *(const f16x8*)(vr + fswz0);
            f16x8 vf1 = *(const f16x8*)(vr + fswz1);
            O[cb] = __builtin_amdgcn_mfma_f32_16x16x32_f16(pf0, vf0, O[cb], 0, 0, 0);
            O[cb] = __builtin_amdgcn_mfma_f32_16x16x32_f16(pf1, vf1, O[cb], 0, 0, 0);
        }
        __builtin_amdgcn_s_setprio(0);
    };

    for (int kt = 0; kt < kN / 64; kt += 2) {
        tile(Ks0, Vs0, Ks1, Vs1, kt);        // even: compute buf0, stage buf1
        tile(Ks1, Vs1, Ks0, Vs0, kt + 1);    // odd : compute buf1, stage buf0
    }

    // ---- epilogue: normalize (per-lane L), gate, store float4 ----
    const float i0 = 1.0f / L[0], i1 = 1.0f / L[1];
    const float i2 = 1.0f / L[2], i3 = 1.0f / L[3];
    const float* Gb = Gw + ((size_t)b * kC) * kN;
    float* Ob = out + ((size_t)b * kC) * kN;
    #pragma unroll
    for (int cb = 0; cb < 8; ++cb) {
        int c = cb * 16 + lm;
        size_t base = (size_t)c * kN + n0 + w * 16 + (lg << 2);
        float4 g = *(const float4*)(Gb + base);
        float4 res;
        res.x = O[cb][0] * i0 * g.x;
        res.y = O[cb][1] * i1 * g.y;
        res.z = O[cb][2] * i2 * g.z;
        res.w = O[cb][3] * i3 * g.w;
        *(float4*)(Ob + base) = res;
    }
}

// ---------------------------------------------------------------------------
extern "C" void kernel_launch(void* const* d_in, const int* in_sizes, int n_in,
                              void* d_out, int out_size, void* d_ws, size_t ws_size,
                              hipStream_t stream) {
    const float* tgt   = (const float*)d_in[0];
    const float* ref   = (const float*)d_in[1];
    const float* W_tgt = (const float*)d_in[2];
    const float* b_tgt = (const float*)d_in[3];
    const float* W_ref = (const float*)d_in[4];
    const float* b_ref = (const float*)d_in[5];
    const float* W_out = (const float*)d_in[6];
    const float* b_out = (const float*)d_in[7];
    float* out = (float*)d_out;

    const size_t QK = (size_t)8 * kN * kCH;              // fp16 -> 4 MB each
    const size_t CV = (size_t)8 * kC * kN;               // fp16 -> 8 MB
    unsigned short* Qw = (unsigned short*)d_ws;          // 4 MB
    unsigned short* Kw = Qw + QK;                        // 4 MB
    unsigned short* Vw = Kw + QK;                        // 8 MB
    float*          Gw = (float*)(Vw + CV);              // 16 MB (total 32 MB)

    proj_fused<<<dim3(32, 16), 256, 0, stream>>>(tgt, ref, W_tgt, W_ref, W_out,
                                                 b_tgt, b_ref, b_out, Qw, Kw, Vw, Gw);
    flash7_kernel<<<dim3(512), 256, 0, stream>>>(Qw, Kw, Vw, Gw, out);
}